// Round 4
// baseline (1151.452 us; speedup 1.0000x reference)
//
#include <hip/hip_runtime.h>
#include <hip/hip_bf16.h>

// Problem constants (match reference)
#define KS_FULL 5
#define INC 64
#define OUTC 64
#define RUN_INC 48
#define RUN_OUTC 48
#define NPTS 200000
#define MPAIR 150000
#define K_RUN 27
#define NPAIRS (K_RUN * MPAIR)                 // 4,050,000
#define NSCAN (NPTS + 1)                       // 200,001
#define SCAN_CHUNK 1024
#define NB1 ((NSCAN + SCAN_CHUNK - 1) / SCAN_CHUNK)   // 196

// d_ws layout (byte offsets)
#define OFF_COUNTS   0u                        // int[200001]
#define OFF_OFFSETS  (1u << 20)                // int[200001]
#define OFF_CURSOR   (2u << 20)                // int[200000]
#define OFF_BSUMS    (3u << 20)                // int[NB1]
#define OFF_WBF      ((3u << 20) + 65536u)     // ushort[27*6*48*8] = 124,416 B
#define OFF_SORTED   (4u << 20)                // int[NPAIRS] = 16.2 MB
#define WS_NEED      ((size_t)OFF_SORTED + (size_t)NPAIRS * 4)

#define WBF_USHORTS (K_RUN * 6 * RUN_OUTC * 8) // 62,208
#define WBF_BYTES   (WBF_USHORTS * 2)          // 124,416

// ---------------------------------------------------------------------------
// prep: extract 27x48x48 center sub-kernel -> bf16, layout [k][ic=i/8][o][i%8]
__global__ __launch_bounds__(256) void prep_wbf(
    const float* __restrict__ kernel, ushort* __restrict__ wbf)
{
    int t = blockIdx.x * 256 + threadIdx.x;
    if (t >= K_RUN * RUN_INC * RUN_OUTC) return;
    int k = t / (RUN_INC * RUN_OUTC);
    int r = t - k * (RUN_INC * RUN_OUTC);
    int i = r / RUN_OUTC;
    int o = r - i * RUN_OUTC;
    int a = k / 9, b = (k / 3) % 3, c = k % 3;
    int kf = (a + 1) * (KS_FULL * KS_FULL) + (b + 1) * KS_FULL + (c + 1);
    float v = kernel[(size_t)kf * (INC * OUTC) + i * OUTC + o];
    __hip_bfloat16 h = __float2bfloat16(v);
    wbf[(((k * 6 + (i >> 3)) * RUN_OUTC + o) << 3) + (i & 7)] =
        *reinterpret_cast<ushort*>(&h);
}

// ---------------------------------------------------------------------------
// hist: 4 pairs per thread (int4 loads), int atomics to L2-resident counts
__global__ __launch_bounds__(256) void hist_kernel(
    const int4* __restrict__ out_idx4, const int4* __restrict__ mask4,
    int* __restrict__ counts)
{
    int t = blockIdx.x * 256 + threadIdx.x;
    if (t >= MPAIR / 4) return;
    int base = blockIdx.y * (MPAIR / 4) + t;
    int4 mk = mask4[base];
    int4 oi = out_idx4[base];
    if (mk.x) atomicAdd(&counts[oi.x], 1);
    if (mk.y) atomicAdd(&counts[oi.y], 1);
    if (mk.z) atomicAdd(&counts[oi.z], 1);
    if (mk.w) atomicAdd(&counts[oi.w], 1);
}

// ---------------------------------------------------------------------------
// scan1: per-1024-chunk exclusive scan; blockSums out
__global__ __launch_bounds__(256) void scan1_kernel(
    const int* __restrict__ counts, int* __restrict__ offsets,
    int* __restrict__ bsums)
{
    __shared__ int sh[2][256];
    int b = blockIdx.x, t = threadIdx.x;
    int gbase = b * SCAN_CHUNK + t * 4;
    int v0 = (gbase + 0 < NSCAN) ? counts[gbase + 0] : 0;
    int v1 = (gbase + 1 < NSCAN) ? counts[gbase + 1] : 0;
    int v2 = (gbase + 2 < NSCAN) ? counts[gbase + 2] : 0;
    int v3 = (gbase + 3 < NSCAN) ? counts[gbase + 3] : 0;
    int tsum = v0 + v1 + v2 + v3;
    sh[0][t] = tsum;
    __syncthreads();
    int src = 0;
    for (int d = 1; d < 256; d <<= 1) {
        int dst = src ^ 1;
        sh[dst][t] = sh[src][t] + ((t >= d) ? sh[src][t - d] : 0);
        __syncthreads();
        src = dst;
    }
    int incl = sh[src][t];
    int excl = incl - tsum;
    if (t == 255) bsums[b] = incl;
    int run = excl;
    if (gbase + 0 < NSCAN) { offsets[gbase + 0] = run; } run += v0;
    if (gbase + 1 < NSCAN) { offsets[gbase + 1] = run; } run += v1;
    if (gbase + 2 < NSCAN) { offsets[gbase + 2] = run; } run += v2;
    if (gbase + 3 < NSCAN) { offsets[gbase + 3] = run; }
}

// scan2: exclusive scan of the NB1 block sums (single block)
__global__ __launch_bounds__(256) void scan2_kernel(int* __restrict__ bsums)
{
    __shared__ int sh[2][256];
    int t = threadIdx.x;
    int v = (t < NB1) ? bsums[t] : 0;
    sh[0][t] = v;
    __syncthreads();
    int src = 0;
    for (int d = 1; d < 256; d <<= 1) {
        int dst = src ^ 1;
        sh[dst][t] = sh[src][t] + ((t >= d) ? sh[src][t - d] : 0);
        __syncthreads();
        src = dst;
    }
    if (t < NB1) bsums[t] = sh[src][t] - v;  // exclusive
}

// scan3: add block offsets; produce cursor copy
__global__ __launch_bounds__(256) void scan3_kernel(
    int* __restrict__ offsets, const int* __restrict__ bsums,
    int* __restrict__ cursor)
{
    int gi = blockIdx.x * 256 + threadIdx.x;
    if (gi < NSCAN) {
        int v = offsets[gi] + bsums[gi >> 10];
        offsets[gi] = v;
        if (gi < NPTS) cursor[gi] = v;
    }
}

// ---------------------------------------------------------------------------
// fill: 4 pairs per thread; scatter packed (in_row | k<<18) into sorted slots
__global__ __launch_bounds__(256) void fill_kernel(
    const int4* __restrict__ in_idx4, const int4* __restrict__ out_idx4,
    const int4* __restrict__ mask4, int* __restrict__ cursor,
    int* __restrict__ sorted)
{
    int t = blockIdx.x * 256 + threadIdx.x;
    if (t >= MPAIR / 4) return;
    int k = blockIdx.y;
    int base = k * (MPAIR / 4) + t;
    int4 mk = mask4[base];
    int4 oi = out_idx4[base];
    int4 ii = in_idx4[base];
    int kk = k << 18;
    if (mk.x) { int pos = atomicAdd(&cursor[oi.x], 1); sorted[pos] = ii.x | kk; }
    if (mk.y) { int pos = atomicAdd(&cursor[oi.y], 1); sorted[pos] = ii.y | kk; }
    if (mk.z) { int pos = atomicAdd(&cursor[oi.z], 1); sorted[pos] = ii.z | kk; }
    if (mk.w) { int pos = atomicAdd(&cursor[oi.w], 1); sorted[pos] = ii.w | kk; }
}

// ---------------------------------------------------------------------------
// accum v2: one wave per output row; lane = out-channel (48 used, 16 dup).
// 2-pair unroll, 4 float2 accumulator chains (8 scalar chains total),
// feature rows loaded half-row-at-a-time as float4 for MLP without VGPR blowup.
// W: all 27 tiles bf16 in LDS, [k][ic][o][8]; lane o's ds_read_b128 is
// <=2-way bank aliased (free, m136; R3 measured 0 conflicts).
#define PKMAC(acc, word, fx, fy)                                  \
    do {                                                          \
        acc.x = fmaf(__uint_as_float((word) << 16), (fx), acc.x); \
        acc.y = fmaf(__uint_as_float((word) & 0xFFFF0000u), (fy), acc.y); \
    } while (0)

__global__ __launch_bounds__(1024) void accum_kernel(
    const float* __restrict__ features, const ushort* __restrict__ wbf,
    const int* __restrict__ offsets, const int* __restrict__ sorted,
    float* __restrict__ out)
{
    extern __shared__ __align__(16) ushort Wlds[];
    {
        const uint4* s4 = (const uint4*)wbf;
        uint4* d4 = (uint4*)Wlds;
        for (int i = threadIdx.x; i < WBF_BYTES / 16; i += 1024) d4[i] = s4[i];
    }
    __syncthreads();

    const int wid  = threadIdx.x >> 6;
    const int lane = threadIdx.x & 63;
    const int o    = (lane < RUN_OUTC) ? lane : (lane - RUN_OUTC); // dup lanes broadcast

    for (int row = blockIdx.x * 16 + wid; row < NPTS; row += 256 * 16) {
        int p = offsets[row];
        const int end = offsets[row + 1];
        float2 a0 = make_float2(0.f, 0.f), a1 = a0, b0 = a0, b1 = a0;

        // two pairs per iteration: independent chains + overlapped loads
        for (; p + 2 <= end; p += 2) {
            const int e0 = sorted[p];
            const int e1 = sorted[p + 1];
            const float4* f0 =
                (const float4*)(features + (size_t)(e0 & 0x3FFFF) * RUN_INC);
            const float4* f1 =
                (const float4*)(features + (size_t)(e1 & 0x3FFFF) * RUN_INC);
            const ushort* w0 = Wlds + (((e0 >> 18) * 6 * RUN_OUTC + o) << 3);
            const ushort* w1 = Wlds + (((e1 >> 18) * 6 * RUN_OUTC + o) << 3);

            #pragma unroll
            for (int h = 0; h < 2; ++h) {          // half-rows: ic 0..2 / 3..5
                float4 A[6], B[6];
                #pragma unroll
                for (int q = 0; q < 6; ++q) { A[q] = f0[h * 6 + q]; B[q] = f1[h * 6 + q]; }
                #pragma unroll
                for (int ic3 = 0; ic3 < 3; ++ic3) {
                    const int ic = h * 3 + ic3;
                    const uint4 wa = *(const uint4*)(w0 + ic * (RUN_OUTC * 8));
                    const uint4 wb = *(const uint4*)(w1 + ic * (RUN_OUTC * 8));
                    PKMAC(a0, wa.x, A[ic3 * 2].x,     A[ic3 * 2].y);
                    PKMAC(a1, wa.y, A[ic3 * 2].z,     A[ic3 * 2].w);
                    PKMAC(a0, wa.z, A[ic3 * 2 + 1].x, A[ic3 * 2 + 1].y);
                    PKMAC(a1, wa.w, A[ic3 * 2 + 1].z, A[ic3 * 2 + 1].w);
                    PKMAC(b0, wb.x, B[ic3 * 2].x,     B[ic3 * 2].y);
                    PKMAC(b1, wb.y, B[ic3 * 2].z,     B[ic3 * 2].w);
                    PKMAC(b0, wb.z, B[ic3 * 2 + 1].x, B[ic3 * 2 + 1].y);
                    PKMAC(b1, wb.w, B[ic3 * 2 + 1].z, B[ic3 * 2 + 1].w);
                }
            }
        }
        if (p < end) {                              // odd-count epilogue
            const int e0 = sorted[p];
            const float4* f0 =
                (const float4*)(features + (size_t)(e0 & 0x3FFFF) * RUN_INC);
            const ushort* w0 = Wlds + (((e0 >> 18) * 6 * RUN_OUTC + o) << 3);
            #pragma unroll
            for (int h = 0; h < 2; ++h) {
                float4 A[6];
                #pragma unroll
                for (int q = 0; q < 6; ++q) A[q] = f0[h * 6 + q];
                #pragma unroll
                for (int ic3 = 0; ic3 < 3; ++ic3) {
                    const int ic = h * 3 + ic3;
                    const uint4 wa = *(const uint4*)(w0 + ic * (RUN_OUTC * 8));
                    PKMAC(a0, wa.x, A[ic3 * 2].x,     A[ic3 * 2].y);
                    PKMAC(a1, wa.y, A[ic3 * 2].z,     A[ic3 * 2].w);
                    PKMAC(a0, wa.z, A[ic3 * 2 + 1].x, A[ic3 * 2 + 1].y);
                    PKMAC(a1, wa.w, A[ic3 * 2 + 1].z, A[ic3 * 2 + 1].w);
                }
            }
        }
        const float s = (a0.x + a0.y) + (a1.x + a1.y)
                      + (b0.x + b0.y) + (b1.x + b1.y);
        if (lane < RUN_OUTC) out[(size_t)row * RUN_OUTC + o] = s;
    }
}

// ---------------------------------------------------------------------------
// Fallback (ws too small): R2 atomic kernel
__global__ __launch_bounds__(256) void conv_gather_scatter(
    const float* __restrict__ features, const float* __restrict__ kernel,
    const int* __restrict__ in_idx, const int* __restrict__ out_idx,
    const int* __restrict__ mask, float* __restrict__ out)
{
    __shared__ float W[RUN_INC][RUN_OUTC];
    const int k = blockIdx.y;
    const int a = k / 9, b = (k / 3) % 3, c = k % 3;
    const int kf = ((a + 1) * KS_FULL + (b + 1)) * KS_FULL + (c + 1);
    const float* __restrict__ Wsrc = kernel + (size_t)kf * (INC * OUTC);
    for (int e = threadIdx.x; e < RUN_INC * RUN_OUTC; e += 256) {
        const int i = e / RUN_OUTC;
        const int o = e - i * RUN_OUTC;
        W[i][o] = Wsrc[i * OUTC + o];
    }
    __syncthreads();
    const int m = blockIdx.x * 256 + threadIdx.x;
    if (m >= MPAIR) return;
    const int pair = k * MPAIR + m;
    if (!mask[pair]) return;
    const int in_row = in_idx[pair], out_row = out_idx[pair];
    const float4* __restrict__ frow = (const float4*)(features + (size_t)in_row * RUN_INC);
    float f[RUN_INC];
    #pragma unroll
    for (int i = 0; i < RUN_INC / 4; ++i) {
        const float4 v = frow[i];
        f[4 * i] = v.x; f[4 * i + 1] = v.y; f[4 * i + 2] = v.z; f[4 * i + 3] = v.w;
    }
    float acc[RUN_OUTC];
    #pragma unroll
    for (int o = 0; o < RUN_OUTC; ++o) acc[o] = 0.0f;
    #pragma unroll 4
    for (int i = 0; i < RUN_INC; ++i) {
        const float fi = f[i];
        const float4* __restrict__ w4 = (const float4*)(&W[i][0]);
        #pragma unroll
        for (int o4 = 0; o4 < RUN_OUTC / 4; ++o4) {
            const float4 w = w4[o4];
            acc[4 * o4 + 0] = fmaf(fi, w.x, acc[4 * o4 + 0]);
            acc[4 * o4 + 1] = fmaf(fi, w.y, acc[4 * o4 + 1]);
            acc[4 * o4 + 2] = fmaf(fi, w.z, acc[4 * o4 + 2]);
            acc[4 * o4 + 3] = fmaf(fi, w.w, acc[4 * o4 + 3]);
        }
    }
    float* __restrict__ orow = out + (size_t)out_row * RUN_OUTC;
    #pragma unroll
    for (int o = 0; o < RUN_OUTC; ++o) unsafeAtomicAdd(orow + o, acc[o]);
}

// ---------------------------------------------------------------------------
extern "C" void kernel_launch(void* const* d_in, const int* in_sizes, int n_in,
                              void* d_out, int out_size, void* d_ws, size_t ws_size,
                              hipStream_t stream) {
    const float* features = (const float*)d_in[0];
    const float* kernel_w = (const float*)d_in[1];
    const int*   in_idx   = (const int*)d_in[2];
    const int*   out_idx  = (const int*)d_in[3];
    const int*   mask     = (const int*)d_in[4];
    float*       out      = (float*)d_out;

    if (ws_size < WS_NEED) {
        hipMemsetAsync(out, 0, (size_t)out_size * sizeof(float), stream);
        dim3 grid((MPAIR + 255) / 256, K_RUN);
        conv_gather_scatter<<<grid, 256, 0, stream>>>(
            features, kernel_w, in_idx, out_idx, mask, out);
        return;
    }

    char* ws = (char*)d_ws;
    int*    counts  = (int*)(ws + OFF_COUNTS);
    int*    offsets = (int*)(ws + OFF_OFFSETS);
    int*    cursor  = (int*)(ws + OFF_CURSOR);
    int*    bsums   = (int*)(ws + OFF_BSUMS);
    ushort* wbf     = (ushort*)(ws + OFF_WBF);
    int*    sorted  = (int*)(ws + OFF_SORTED);

    hipMemsetAsync(counts, 0, (size_t)NSCAN * sizeof(int), stream);

    prep_wbf<<<(K_RUN * RUN_INC * RUN_OUTC + 255) / 256, 256, 0, stream>>>(
        kernel_w, wbf);

    dim3 pgrid((MPAIR / 4 + 255) / 256, K_RUN);
    hist_kernel<<<pgrid, 256, 0, stream>>>(
        (const int4*)out_idx, (const int4*)mask, counts);

    scan1_kernel<<<NB1, 256, 0, stream>>>(counts, offsets, bsums);
    scan2_kernel<<<1, 256, 0, stream>>>(bsums);
    scan3_kernel<<<(NSCAN + 255) / 256, 256, 0, stream>>>(offsets, bsums, cursor);

    fill_kernel<<<pgrid, 256, 0, stream>>>(
        (const int4*)in_idx, (const int4*)out_idx, (const int4*)mask,
        cursor, sorted);

    accum_kernel<<<256, 1024, WBF_BYTES, stream>>>(
        features, wbf, offsets, sorted, out);
}

// Round 5
// 700.682 us; speedup vs baseline: 1.6433x; 1.6433x over previous
//
#include <hip/hip_runtime.h>
#include <hip/hip_bf16.h>

// Problem constants (match reference)
#define KS_FULL 5
#define INC 64
#define OUTC 64
#define RUN_INC 48
#define RUN_OUTC 48
#define NPTS 200000
#define MPAIR 150000
#define K_RUN 27
#define NPAIRS (K_RUN * MPAIR)                 // 4,050,000
#define NSCAN (NPTS + 1)                       // 200,001
#define SCAN_CHUNK 1024
#define NB1 ((NSCAN + SCAN_CHUNK - 1) / SCAN_CHUNK)   // 196

// ---------------------------------------------------------------------------
// d_ws layout (byte offsets)
#define OFF_COUNTS   0u                        // int[200001]
#define OFF_OFFSETS  (1u << 20)                // int[200001]
#define OFF_CURSOR   (2u << 20)                // int[200000]
#define OFF_BSUMS    (3u << 20)                // int[NB1]
#define OFF_WBF      ((3u << 20) + 65536u)     // ushort[27*6*48*8] = 124,416 B
#define OFF_FBF      (4u << 20)                // ushort[200000*48] = 19,200,000 B
#define OFF_SORTED_BIG (24u << 20)             // int[NPAIRS] = 16.2 MB
#define OFF_SORTED_MID (4u << 20)              // mid path reuses 4MB+ region
#define WS_BIG  ((size_t)OFF_SORTED_BIG + (size_t)NPAIRS * 4)  // ~39.5 MB
#define WS_MID  ((size_t)OFF_SORTED_MID + (size_t)NPAIRS * 4)  // ~19.5 MB

#define WBF_U4    (K_RUN * 6 * RUN_OUTC)       // 7776 uint4 (16B per (k,ic,o))
#define WBF_BYTES (WBF_U4 * 16)                // 124,416
#define KSPLIT    14                           // k < 14 from LDS, rest from L2
#define WLDS_U4   (KSPLIT * 6 * RUN_OUTC)      // 4032 uint4 = 64,512 B

#define ROWS_PER_WAVE 25
#define ACC_BLOCKS    500                      // 500*16 waves * 25 rows = 200,000

// ---------------------------------------------------------------------------
// bf16 helpers: RNE pack; dot2 (HW v_dot2_f32_bf16 if available, exact fallback)
__device__ __forceinline__ unsigned short bf_rne(float x) {
    unsigned u = __float_as_uint(x);
    u += 0x7FFFu + ((u >> 16) & 1u);           // round-to-nearest-even
    return (unsigned short)(u >> 16);
}
__device__ __forceinline__ unsigned pack2bf(float lo, float hi) {
    return (unsigned)bf_rne(lo) | ((unsigned)bf_rne(hi) << 16);
}

#if defined(__has_builtin)
#if __has_builtin(__builtin_amdgcn_fdot2_f32_bf16)
#define HAVE_DOT2 1
#endif
#endif

#ifdef HAVE_DOT2
typedef __bf16 bf16x2 __attribute__((ext_vector_type(2)));
__device__ __forceinline__ float dot2bf(unsigned w, unsigned f, float c) {
    return __builtin_amdgcn_fdot2_f32_bf16(__builtin_bit_cast(bf16x2, w),
                                           __builtin_bit_cast(bf16x2, f), c, false);
}
#else
__device__ __forceinline__ float dot2bf(unsigned w, unsigned f, float c) {
    c = fmaf(__uint_as_float(w << 16), __uint_as_float(f << 16), c);
    c = fmaf(__uint_as_float(w & 0xFFFF0000u), __uint_as_float(f & 0xFFFF0000u), c);
    return c;
}
#endif

// ---------------------------------------------------------------------------
// prep: 27x48x48 center sub-kernel -> bf16 RNE, layout [k][ic=i/8][o][i%8]
__global__ __launch_bounds__(256) void prep_wbf(
    const float* __restrict__ kernel, unsigned short* __restrict__ wbf)
{
    int t = blockIdx.x * 256 + threadIdx.x;
    if (t >= K_RUN * RUN_INC * RUN_OUTC) return;
    int k = t / (RUN_INC * RUN_OUTC);
    int r = t - k * (RUN_INC * RUN_OUTC);
    int i = r / RUN_OUTC;
    int o = r - i * RUN_OUTC;
    int a = k / 9, b = (k / 3) % 3, c = k % 3;
    int kf = (a + 1) * (KS_FULL * KS_FULL) + (b + 1) * KS_FULL + (c + 1);
    float v = kernel[(size_t)kf * (INC * OUTC) + i * OUTC + o];
    wbf[(((k * 6 + (i >> 3)) * RUN_OUTC + o) << 3) + (i & 7)] = bf_rne(v);
}

// prep: features fp32 -> packed bf16 (8 floats / thread)
__global__ __launch_bounds__(256) void prep_fbf(
    const float4* __restrict__ f4, uint4* __restrict__ fb4)
{
    int t = blockIdx.x * 256 + threadIdx.x;
    if (t >= (NPTS * RUN_INC) / 8) return;
    float4 a = f4[2 * t], b = f4[2 * t + 1];
    uint4 o;
    o.x = pack2bf(a.x, a.y); o.y = pack2bf(a.z, a.w);
    o.z = pack2bf(b.x, b.y); o.w = pack2bf(b.z, b.w);
    fb4[t] = o;
}

// ---------------------------------------------------------------------------
// hist: 4 pairs per thread (int4 loads), int atomics to L2-resident counts
__global__ __launch_bounds__(256) void hist_kernel(
    const int4* __restrict__ out_idx4, const int4* __restrict__ mask4,
    int* __restrict__ counts)
{
    int t = blockIdx.x * 256 + threadIdx.x;
    if (t >= MPAIR / 4) return;
    int base = blockIdx.y * (MPAIR / 4) + t;
    int4 mk = mask4[base];
    int4 oi = out_idx4[base];
    if (mk.x) atomicAdd(&counts[oi.x], 1);
    if (mk.y) atomicAdd(&counts[oi.y], 1);
    if (mk.z) atomicAdd(&counts[oi.z], 1);
    if (mk.w) atomicAdd(&counts[oi.w], 1);
}

// ---------------------------------------------------------------------------
// scan1/2/3: exclusive scan of counts -> offsets (+ cursor copy)
__global__ __launch_bounds__(256) void scan1_kernel(
    const int* __restrict__ counts, int* __restrict__ offsets,
    int* __restrict__ bsums)
{
    __shared__ int sh[2][256];
    int b = blockIdx.x, t = threadIdx.x;
    int gbase = b * SCAN_CHUNK + t * 4;
    int v0 = (gbase + 0 < NSCAN) ? counts[gbase + 0] : 0;
    int v1 = (gbase + 1 < NSCAN) ? counts[gbase + 1] : 0;
    int v2 = (gbase + 2 < NSCAN) ? counts[gbase + 2] : 0;
    int v3 = (gbase + 3 < NSCAN) ? counts[gbase + 3] : 0;
    int tsum = v0 + v1 + v2 + v3;
    sh[0][t] = tsum;
    __syncthreads();
    int src = 0;
    for (int d = 1; d < 256; d <<= 1) {
        int dst = src ^ 1;
        sh[dst][t] = sh[src][t] + ((t >= d) ? sh[src][t - d] : 0);
        __syncthreads();
        src = dst;
    }
    int incl = sh[src][t];
    int excl = incl - tsum;
    if (t == 255) bsums[b] = incl;
    int run = excl;
    if (gbase + 0 < NSCAN) { offsets[gbase + 0] = run; } run += v0;
    if (gbase + 1 < NSCAN) { offsets[gbase + 1] = run; } run += v1;
    if (gbase + 2 < NSCAN) { offsets[gbase + 2] = run; } run += v2;
    if (gbase + 3 < NSCAN) { offsets[gbase + 3] = run; }
}

__global__ __launch_bounds__(256) void scan2_kernel(int* __restrict__ bsums)
{
    __shared__ int sh[2][256];
    int t = threadIdx.x;
    int v = (t < NB1) ? bsums[t] : 0;
    sh[0][t] = v;
    __syncthreads();
    int src = 0;
    for (int d = 1; d < 256; d <<= 1) {
        int dst = src ^ 1;
        sh[dst][t] = sh[src][t] + ((t >= d) ? sh[src][t - d] : 0);
        __syncthreads();
        src = dst;
    }
    if (t < NB1) bsums[t] = sh[src][t] - v;  // exclusive
}

__global__ __launch_bounds__(256) void scan3_kernel(
    int* __restrict__ offsets, const int* __restrict__ bsums,
    int* __restrict__ cursor)
{
    int gi = blockIdx.x * 256 + threadIdx.x;
    if (gi < NSCAN) {
        int v = offsets[gi] + bsums[gi >> 10];
        offsets[gi] = v;
        if (gi < NPTS) cursor[gi] = v;
    }
}

// ---------------------------------------------------------------------------
// fill: 4 pairs per thread; scatter packed (in_row | k<<18) into sorted slots
__global__ __launch_bounds__(256) void fill_kernel(
    const int4* __restrict__ in_idx4, const int4* __restrict__ out_idx4,
    const int4* __restrict__ mask4, int* __restrict__ cursor,
    int* __restrict__ sorted)
{
    int t = blockIdx.x * 256 + threadIdx.x;
    if (t >= MPAIR / 4) return;
    int k = blockIdx.y;
    int base = k * (MPAIR / 4) + t;
    int4 mk = mask4[base];
    int4 oi = out_idx4[base];
    int4 ii = in_idx4[base];
    int kk = k << 18;
    if (mk.x) { int pos = atomicAdd(&cursor[oi.x], 1); sorted[pos] = ii.x | kk; }
    if (mk.y) { int pos = atomicAdd(&cursor[oi.y], 1); sorted[pos] = ii.y | kk; }
    if (mk.z) { int pos = atomicAdd(&cursor[oi.z], 1); sorted[pos] = ii.z | kk; }
    if (mk.w) { int pos = atomicAdd(&cursor[oi.w], 1); sorted[pos] = ii.w | kk; }
}

// ---------------------------------------------------------------------------
// accum v3 ("4-slot"): one wave processes 4 pairs at a time for one row.
// lane = slot*16 + c; slot s handles pair p+s; lane owns channels c,c+16,c+32.
// All 64 lanes useful. W hybrid: k<KSPLIT from LDS (64.5KB -> 2 blocks/CU,
// 8 waves/SIMD), k>=KSPLIT from L2 (124KB table, L2-resident).
// Each 16-lane b128 phase reads a contiguous 256B chunk -> conflict-free.
#define DOT12(wv, fv)                                              \
    do {                                                           \
        a0 = dot2bf(w0.x, fv.x, a0); a0 = dot2bf(w0.y, fv.y, a0);  \
        a0 = dot2bf(w0.z, fv.z, a0); a0 = dot2bf(w0.w, fv.w, a0);  \
        a1 = dot2bf(w1.x, fv.x, a1); a1 = dot2bf(w1.y, fv.y, a1);  \
        a1 = dot2bf(w1.z, fv.z, a1); a1 = dot2bf(w1.w, fv.w, a1);  \
        a2 = dot2bf(w2.x, fv.x, a2); a2 = dot2bf(w2.y, fv.y, a2);  \
        a2 = dot2bf(w2.z, fv.z, a2); a2 = dot2bf(w2.w, fv.w, a2);  \
    } while (0)

__global__ __launch_bounds__(1024, 8) void accum4_kernel(
    const uint4* __restrict__ fbf4,     // bf16 features, 6 uint4 per row
    const uint4* __restrict__ wbf4,     // 27*6*48 uint4, k-major
    const int* __restrict__ offsets,
    const int* __restrict__ sorted,
    float* __restrict__ out)
{
    __shared__ uint4 Wl4[WLDS_U4];
    for (int i = threadIdx.x; i < WLDS_U4; i += 1024) Wl4[i] = wbf4[i];
    __syncthreads();

    const int lane = threadIdx.x & 63;
    const int slot = lane >> 4;          // 0..3 : pair slot
    const int c    = lane & 15;          // base channel 0..15
    const int wgid = blockIdx.x * 16 + (threadIdx.x >> 6);

    const int row0 = wgid * ROWS_PER_WAVE;
    const int row1 = min(row0 + ROWS_PER_WAVE, NPTS);
    if (row0 >= NPTS) return;

    int start = offsets[row0];
    for (int row = row0; row < row1; ++row) {
        const int end = offsets[row + 1];
        float a0 = 0.f, a1 = 0.f, a2 = 0.f;
        for (int p = start; p < end; p += 4) {
            const int ps = p + slot;
            if (ps < end) {
                const int e  = sorted[ps];           // uniform per 16-lane group
                const int fb = (e & 0x3FFFF) * 6;
                const int kk = e >> 18;
                const int wb = kk * (6 * RUN_OUTC);
                if (kk < KSPLIT) {
                    #pragma unroll
                    for (int ic = 0; ic < 6; ++ic) {
                        const uint4 f  = fbf4[fb + ic];
                        const uint4 w0 = Wl4[wb + ic * RUN_OUTC + c];
                        const uint4 w1 = Wl4[wb + ic * RUN_OUTC + c + 16];
                        const uint4 w2 = Wl4[wb + ic * RUN_OUTC + c + 32];
                        DOT12(w, f);
                    }
                } else {
                    #pragma unroll
                    for (int ic = 0; ic < 6; ++ic) {
                        const uint4 f  = fbf4[fb + ic];
                        const uint4 w0 = wbf4[wb + ic * RUN_OUTC + c];
                        const uint4 w1 = wbf4[wb + ic * RUN_OUTC + c + 16];
                        const uint4 w2 = wbf4[wb + ic * RUN_OUTC + c + 32];
                        DOT12(w, f);
                    }
                }
            }
        }
        // sum the 4 slots: lanes {c, c+16, c+32, c+48} hold same channels
        a0 += __shfl_xor(a0, 16); a0 += __shfl_xor(a0, 32);
        a1 += __shfl_xor(a1, 16); a1 += __shfl_xor(a1, 32);
        a2 += __shfl_xor(a2, 16); a2 += __shfl_xor(a2, 32);
        if (slot == 0) {
            float* orow = out + (size_t)row * RUN_OUTC;
            orow[c]      = a0;
            orow[c + 16] = a1;
            orow[c + 32] = a2;
        }
        start = end;                      // contiguous rows share boundaries
    }
}

// ---------------------------------------------------------------------------
// accum mid (ws too small for fbf): R4-style, fp32 features, all-27 LDS
#define PKMAC(acc, word, fx, fy)                                  \
    do {                                                          \
        acc.x = fmaf(__uint_as_float((word) << 16), (fx), acc.x); \
        acc.y = fmaf(__uint_as_float((word) & 0xFFFF0000u), (fy), acc.y); \
    } while (0)

__global__ __launch_bounds__(1024) void accum_mid_kernel(
    const float* __restrict__ features, const unsigned short* __restrict__ wbf,
    const int* __restrict__ offsets, const int* __restrict__ sorted,
    float* __restrict__ out)
{
    extern __shared__ __align__(16) unsigned short Wlds[];
    {
        const uint4* s4 = (const uint4*)wbf;
        uint4* d4 = (uint4*)Wlds;
        for (int i = threadIdx.x; i < WBF_BYTES / 16; i += 1024) d4[i] = s4[i];
    }
    __syncthreads();

    const int wid  = threadIdx.x >> 6;
    const int lane = threadIdx.x & 63;
    const int o    = (lane < RUN_OUTC) ? lane : (lane - RUN_OUTC);

    for (int row = blockIdx.x * 16 + wid; row < NPTS; row += 256 * 16) {
        int p = offsets[row];
        const int end = offsets[row + 1];
        float2 a0 = make_float2(0.f, 0.f), a1 = a0;
        for (; p < end; ++p) {
            const int e = sorted[p];
            const float4* f0 =
                (const float4*)(features + (size_t)(e & 0x3FFFF) * RUN_INC);
            const unsigned short* w0 = Wlds + (((e >> 18) * 6 * RUN_OUTC + o) << 3);
            #pragma unroll
            for (int ic = 0; ic < 6; ++ic) {
                const float4 A0 = f0[ic * 2], A1 = f0[ic * 2 + 1];
                const uint4 wa = *(const uint4*)(w0 + ic * (RUN_OUTC * 8));
                PKMAC(a0, wa.x, A0.x, A0.y);
                PKMAC(a1, wa.y, A0.z, A0.w);
                PKMAC(a0, wa.z, A1.x, A1.y);
                PKMAC(a1, wa.w, A1.z, A1.w);
            }
        }
        if (lane < RUN_OUTC)
            out[(size_t)row * RUN_OUTC + o] = (a0.x + a0.y) + (a1.x + a1.y);
    }
}

// ---------------------------------------------------------------------------
// Fallback (ws tiny): R2 atomic kernel
__global__ __launch_bounds__(256) void conv_gather_scatter(
    const float* __restrict__ features, const float* __restrict__ kernel,
    const int* __restrict__ in_idx, const int* __restrict__ out_idx,
    const int* __restrict__ mask, float* __restrict__ out)
{
    __shared__ float W[RUN_INC][RUN_OUTC];
    const int k = blockIdx.y;
    const int a = k / 9, b = (k / 3) % 3, c = k % 3;
    const int kf = ((a + 1) * KS_FULL + (b + 1)) * KS_FULL + (c + 1);
    const float* __restrict__ Wsrc = kernel + (size_t)kf * (INC * OUTC);
    for (int e = threadIdx.x; e < RUN_INC * RUN_OUTC; e += 256) {
        const int i = e / RUN_OUTC;
        const int o = e - i * RUN_OUTC;
        W[i][o] = Wsrc[i * OUTC + o];
    }
    __syncthreads();
    const int m = blockIdx.x * 256 + threadIdx.x;
    if (m >= MPAIR) return;
    const int pair = k * MPAIR + m;
    if (!mask[pair]) return;
    const int in_row = in_idx[pair], out_row = out_idx[pair];
    const float4* __restrict__ frow = (const float4*)(features + (size_t)in_row * RUN_INC);
    float f[RUN_INC];
    #pragma unroll
    for (int i = 0; i < RUN_INC / 4; ++i) {
        const float4 v = frow[i];
        f[4 * i] = v.x; f[4 * i + 1] = v.y; f[4 * i + 2] = v.z; f[4 * i + 3] = v.w;
    }
    float acc[RUN_OUTC];
    #pragma unroll
    for (int o = 0; o < RUN_OUTC; ++o) acc[o] = 0.0f;
    #pragma unroll 4
    for (int i = 0; i < RUN_INC; ++i) {
        const float fi = f[i];
        const float4* __restrict__ w4 = (const float4*)(&W[i][0]);
        #pragma unroll
        for (int o4 = 0; o4 < RUN_OUTC / 4; ++o4) {
            const float4 w = w4[o4];
            acc[4 * o4 + 0] = fmaf(fi, w.x, acc[4 * o4 + 0]);
            acc[4 * o4 + 1] = fmaf(fi, w.y, acc[4 * o4 + 1]);
            acc[4 * o4 + 2] = fmaf(fi, w.z, acc[4 * o4 + 2]);
            acc[4 * o4 + 3] = fmaf(fi, w.w, acc[4 * o4 + 3]);
        }
    }
    float* __restrict__ orow = out + (size_t)out_row * RUN_OUTC;
    #pragma unroll
    for (int o = 0; o < RUN_OUTC; ++o) unsafeAtomicAdd(orow + o, acc[o]);
}

// ---------------------------------------------------------------------------
extern "C" void kernel_launch(void* const* d_in, const int* in_sizes, int n_in,
                              void* d_out, int out_size, void* d_ws, size_t ws_size,
                              hipStream_t stream) {
    const float* features = (const float*)d_in[0];
    const float* kernel_w = (const float*)d_in[1];
    const int*   in_idx   = (const int*)d_in[2];
    const int*   out_idx  = (const int*)d_in[3];
    const int*   mask     = (const int*)d_in[4];
    float*       out      = (float*)d_out;

    if (ws_size < WS_MID) {
        hipMemsetAsync(out, 0, (size_t)out_size * sizeof(float), stream);
        dim3 grid((MPAIR + 255) / 256, K_RUN);
        conv_gather_scatter<<<grid, 256, 0, stream>>>(
            features, kernel_w, in_idx, out_idx, mask, out);
        return;
    }

    char* ws = (char*)d_ws;
    int*            counts  = (int*)(ws + OFF_COUNTS);
    int*            offsets = (int*)(ws + OFF_OFFSETS);
    int*            cursor  = (int*)(ws + OFF_CURSOR);
    int*            bsums   = (int*)(ws + OFF_BSUMS);
    unsigned short* wbf     = (unsigned short*)(ws + OFF_WBF);
    const bool big = (ws_size >= WS_BIG);
    int* sorted = (int*)(ws + (big ? OFF_SORTED_BIG : OFF_SORTED_MID));

    hipMemsetAsync(counts, 0, (size_t)NSCAN * sizeof(int), stream);

    prep_wbf<<<(K_RUN * RUN_INC * RUN_OUTC + 255) / 256, 256, 0, stream>>>(
        kernel_w, wbf);

    dim3 pgrid((MPAIR / 4 + 255) / 256, K_RUN);
    hist_kernel<<<pgrid, 256, 0, stream>>>(
        (const int4*)out_idx, (const int4*)mask, counts);

    scan1_kernel<<<NB1, 256, 0, stream>>>(counts, offsets, bsums);
    scan2_kernel<<<1, 256, 0, stream>>>(bsums);
    scan3_kernel<<<(NSCAN + 255) / 256, 256, 0, stream>>>(offsets, bsums, cursor);

    fill_kernel<<<pgrid, 256, 0, stream>>>(
        (const int4*)in_idx, (const int4*)out_idx, (const int4*)mask,
        cursor, sorted);

    if (big) {
        uint4* fbf4 = (uint4*)(ws + OFF_FBF);
        prep_fbf<<<((NPTS * RUN_INC / 8) + 255) / 256, 256, 0, stream>>>(
            (const float4*)features, fbf4);
        accum4_kernel<<<ACC_BLOCKS, 1024, 0, stream>>>(
            fbf4, (const uint4*)wbf, offsets, sorted, out);
    } else {
        accum_mid_kernel<<<256, 1024, WBF_BYTES, stream>>>(
            features, wbf, offsets, sorted, out);
    }
}